// Round 2
// baseline (542.809 us; speedup 1.0000x reference)
//
#include <hip/hip_runtime.h>
#include <math.h>

#define N_NODES 50000
#define E_EDGES 1600000
#define NE_TOT  (E_EDGES + N_NODES)

// ---------------- CSR build ----------------

__global__ void k_hist(const int* __restrict__ ei, int* __restrict__ deg) {
    int i = blockIdx.x * 256 + threadIdx.x;
    if (i < E_EDGES) {
        int d = ei[E_EDGES + i];
        atomicAdd(&deg[d], 1);
    } else if (i < NE_TOT) {
        atomicAdd(&deg[i - E_EDGES], 1);   // self loop
    }
}

// block handles 1024 elements -> partial sum
__global__ void k_scan1(const int* __restrict__ deg, int* __restrict__ part) {
    __shared__ int sh[256];
    int base = blockIdx.x * 1024;
    int t = threadIdx.x;
    int s = 0;
    #pragma unroll
    for (int j = 0; j < 4; j++) {
        int i = base + t * 4 + j;
        s += (i < N_NODES) ? deg[i] : 0;
    }
    sh[t] = s; __syncthreads();
    for (int d = 128; d > 0; d >>= 1) {
        if (t < d) sh[t] += sh[t + d];
        __syncthreads();
    }
    if (t == 0) part[blockIdx.x] = sh[0];
}

// single block: exclusive-scan the partials, write total to row_start[N]
__global__ void k_scan2(int* part, int* __restrict__ row_start, int nb) {
    __shared__ int sh[256];
    int t = threadIdx.x;
    int v = (t < nb) ? part[t] : 0;
    sh[t] = v; __syncthreads();
    for (int d = 1; d < 256; d <<= 1) {
        int x = (t >= d) ? sh[t - d] : 0;
        __syncthreads();
        sh[t] += x;
        __syncthreads();
    }
    if (t < nb) part[t] = sh[t] - v;       // exclusive
    if (t == 255) row_start[N_NODES] = sh[255];
}

__global__ void k_scan3(const int* __restrict__ deg, const int* __restrict__ part,
                        int* __restrict__ row_start, int* __restrict__ cursor) {
    __shared__ int sh[256];
    int base = blockIdx.x * 1024;
    int t = threadIdx.x;
    int v[4]; int ts = 0;
    #pragma unroll
    for (int j = 0; j < 4; j++) {
        int i = base + t * 4 + j;
        v[j] = (i < N_NODES) ? deg[i] : 0;
        ts += v[j];
    }
    sh[t] = ts; __syncthreads();
    for (int d = 1; d < 256; d <<= 1) {
        int x = (t >= d) ? sh[t - d] : 0;
        __syncthreads();
        sh[t] += x;
        __syncthreads();
    }
    int excl = sh[t] - ts + part[blockIdx.x];
    #pragma unroll
    for (int j = 0; j < 4; j++) {
        int i = base + t * 4 + j;
        if (i < N_NODES) { row_start[i] = excl; cursor[i] = excl; excl += v[j]; }
    }
}

__global__ void k_scatter(const int* __restrict__ ei, int* __restrict__ cursor,
                          int* __restrict__ col) {
    int i = blockIdx.x * 256 + threadIdx.x;
    if (i >= NE_TOT) return;
    int s, d;
    if (i < E_EDGES) { s = ei[i]; d = ei[E_EDGES + i]; }
    else             { s = d = i - E_EDGES; }
    int pos = atomicAdd(&cursor[d], 1);
    col[pos] = s;
}

// ---------------- GEMM (128x128) + attention logits ----------------
// h = X @ W  (row-major, [N,128]@[128,128]); a_s[n][h] = sum_c h[n,h*32+c]*attS[h*32+c]
// block = 256 threads, 32 rows per block. LDS: W half-tile 64x128 (32KB) + x tile 32x64 (8KB).
__global__ __launch_bounds__(256) void k_gemm_att(
    const float* __restrict__ X, const float* __restrict__ W,
    const float* __restrict__ attS, const float* __restrict__ attD,
    float* __restrict__ Hout, float* __restrict__ a_s, float* __restrict__ a_d) {
    __shared__ float Wl[64 * 128];
    __shared__ float xs[32 * 64];
    int t = threadIdx.x;
    int g = t >> 5, cl = t & 31, c4 = cl * 4;
    int rowbase = blockIdx.x * 32;
    float4 acc[4];
    #pragma unroll
    for (int rr = 0; rr < 4; rr++) acc[rr] = make_float4(0.f, 0.f, 0.f, 0.f);

    for (int kp = 0; kp < 2; kp++) {
        __syncthreads();
        // stage W half (64 rows of k)
        #pragma unroll
        for (int j = 0; j < 8; j++) {
            int f4 = t + 256 * j;            // 0..2047
            int kk = f4 >> 5, cg = f4 & 31;
            *(float4*)&Wl[kk * 128 + cg * 4] =
                *(const float4*)&W[(kp * 64 + kk) * 128 + cg * 4];
        }
        // stage x tile (32 rows x 64 k)
        #pragma unroll
        for (int j = 0; j < 2; j++) {
            int f4 = t + 256 * j;            // 0..511
            int r = f4 >> 4, k4 = f4 & 15;
            int grow = rowbase + r;
            float4 xv = make_float4(0.f, 0.f, 0.f, 0.f);
            if (grow < N_NODES) xv = *(const float4*)&X[grow * 128 + kp * 64 + k4 * 4];
            *(float4*)&xs[r * 64 + k4 * 4] = xv;
        }
        __syncthreads();
        #pragma unroll
        for (int k4 = 0; k4 < 16; k4++) {
            float4 xv[4];
            #pragma unroll
            for (int rr = 0; rr < 4; rr++)
                xv[rr] = *(float4*)&xs[(g * 4 + rr) * 64 + k4 * 4];
            #pragma unroll
            for (int kk = 0; kk < 4; kk++) {
                float4 wv = *(float4*)&Wl[(k4 * 4 + kk) * 128 + c4];
                #pragma unroll
                for (int rr = 0; rr < 4; rr++) {
                    float xc = (kk == 0) ? xv[rr].x : (kk == 1) ? xv[rr].y
                             : (kk == 2) ? xv[rr].z : xv[rr].w;
                    acc[rr].x += xc * wv.x;
                    acc[rr].y += xc * wv.y;
                    acc[rr].z += xc * wv.z;
                    acc[rr].w += xc * wv.w;
                }
            }
        }
    }

    // epilogue: write h, compute attention logits
    float4 as4 = *(const float4*)&attS[c4];
    float4 ad4 = *(const float4*)&attD[c4];
    int head = cl >> 3;
    #pragma unroll
    for (int rr = 0; rr < 4; rr++) {
        int grow = rowbase + g * 4 + rr;
        float4 a = acc[rr];
        if (grow < N_NODES) *(float4*)&Hout[grow * 128 + c4] = a;
        float ps = a.x * as4.x + a.y * as4.y + a.z * as4.z + a.w * as4.w;
        float pd = a.x * ad4.x + a.y * ad4.y + a.z * ad4.z + a.w * ad4.w;
        ps += __shfl_xor(ps, 1); ps += __shfl_xor(ps, 2); ps += __shfl_xor(ps, 4);
        pd += __shfl_xor(pd, 1); pd += __shfl_xor(pd, 2); pd += __shfl_xor(pd, 4);
        if ((cl & 7) == 0 && grow < N_NODES) {
            a_s[grow * 4 + head] = ps;
            a_d[grow * 4 + head] = pd;
        }
    }
}

// ---------------- Attention aggregation ----------------

__device__ inline float sel4(float4 v, int i) {
    float r = v.x;
    if (i == 1) r = v.y;
    if (i == 2) r = v.z;
    if (i == 3) r = v.w;
    return r;
}

__device__ inline void merge1(float& m, float& s, float mo, float so) {
    float mn = fmaxf(m, mo);
    s = s * __expf(m - mn) + so * __expf(mo - mn);
    m = mn;
}

template<int DO_ELU>
__global__ __launch_bounds__(256) void k_agg(
    const float* __restrict__ Hin, const float* __restrict__ a_s,
    const float* __restrict__ a_d, const int* __restrict__ row_start,
    const int* __restrict__ col, const float* __restrict__ bias,
    float* __restrict__ Hout) {
    int wid = threadIdx.x >> 6;
    int lane = threadIdx.x & 63;
    int node = blockIdx.x * 4 + wid;
    if (node >= N_NODES) return;
    int beg = row_start[node], end = row_start[node + 1];
    float4 ad4 = *(const float4*)&a_d[node * 4];

    // phase 1: online softmax stats (per head), edge-parallel over 64 lanes
    float4 m = make_float4(-1e30f, -1e30f, -1e30f, -1e30f);
    float4 s = make_float4(0.f, 0.f, 0.f, 0.f);
    for (int j = beg + lane; j < end; j += 64) {
        int src = col[j];
        float4 av = *(const float4*)&a_s[src * 4];
        float4 e;
        e.x = av.x + ad4.x; e.x = e.x > 0.f ? e.x : 0.2f * e.x;
        e.y = av.y + ad4.y; e.y = e.y > 0.f ? e.y : 0.2f * e.y;
        e.z = av.z + ad4.z; e.z = e.z > 0.f ? e.z : 0.2f * e.z;
        e.w = av.w + ad4.w; e.w = e.w > 0.f ? e.w : 0.2f * e.w;
        float mn;
        mn = fmaxf(m.x, e.x); s.x = s.x * __expf(m.x - mn) + __expf(e.x - mn); m.x = mn;
        mn = fmaxf(m.y, e.y); s.y = s.y * __expf(m.y - mn) + __expf(e.y - mn); m.y = mn;
        mn = fmaxf(m.z, e.z); s.z = s.z * __expf(m.z - mn) + __expf(e.z - mn); m.z = mn;
        mn = fmaxf(m.w, e.w); s.w = s.w * __expf(m.w - mn) + __expf(e.w - mn); m.w = mn;
    }
    #pragma unroll
    for (int off = 32; off > 0; off >>= 1) {
        float mo, so;
        mo = __shfl_xor(m.x, off); so = __shfl_xor(s.x, off); merge1(m.x, s.x, mo, so);
        mo = __shfl_xor(m.y, off); so = __shfl_xor(s.y, off); merge1(m.y, s.y, mo, so);
        mo = __shfl_xor(m.z, off); so = __shfl_xor(s.z, off); merge1(m.z, s.z, mo, so);
        mo = __shfl_xor(m.w, off); so = __shfl_xor(s.w, off); merge1(m.w, s.w, mo, so);
    }
    float4 inv;
    inv.x = 1.f / (s.x + 1e-16f);
    inv.y = 1.f / (s.y + 1e-16f);
    inv.z = 1.f / (s.z + 1e-16f);
    inv.w = 1.f / (s.w + 1e-16f);

    // phase 2: channel-parallel, 2 edge slots per wave
    int slot = lane >> 5, cl = lane & 31, c4 = cl * 4, head = cl >> 3;
    float mh  = sel4(m, head);
    float ih  = sel4(inv, head);
    float adh = sel4(ad4, head);
    float4 acc = make_float4(0.f, 0.f, 0.f, 0.f);
    for (int j = beg + slot; j < end; j += 2) {
        int src = col[j];
        float eh = a_s[src * 4 + head] + adh;
        eh = eh > 0.f ? eh : 0.2f * eh;
        float alpha = __expf(eh - mh) * ih;
        float4 hv = *(const float4*)&Hin[src * 128 + c4];
        acc.x += alpha * hv.x;
        acc.y += alpha * hv.y;
        acc.z += alpha * hv.z;
        acc.w += alpha * hv.w;
    }
    acc.x += __shfl_xor(acc.x, 32);
    acc.y += __shfl_xor(acc.y, 32);
    acc.z += __shfl_xor(acc.z, 32);
    acc.w += __shfl_xor(acc.w, 32);
    if (slot == 0) {
        float4 bv = *(const float4*)&bias[c4];
        float4 o;
        o.x = acc.x + bv.x; o.y = acc.y + bv.y;
        o.z = acc.z + bv.z; o.w = acc.w + bv.w;
        if (DO_ELU) {
            o.x = o.x > 0.f ? o.x : expm1f(o.x);
            o.y = o.y > 0.f ? o.y : expm1f(o.y);
            o.z = o.z > 0.f ? o.z : expm1f(o.z);
            o.w = o.w > 0.f ? o.w : expm1f(o.w);
        }
        *(float4*)&Hout[node * 128 + c4] = o;
    }
}

// ---------------- Output projection [N,128]@[128,8] ----------------

__global__ __launch_bounds__(256) void k_out(
    const float* __restrict__ Hin, const float* __restrict__ Wout,
    const float* __restrict__ bout, float* __restrict__ out) {
    __shared__ float Wl[128 * 8];
    __shared__ float bl[8];
    int t = threadIdx.x;
    for (int j = t; j < 1024; j += 256) Wl[j] = Wout[j];
    if (t < 8) bl[t] = bout[t];
    __syncthreads();
    int gid = blockIdx.x * 256 + t;
    int row = gid >> 3, o = gid & 7;
    if (row >= N_NODES) return;
    const float* hr = &Hin[row * 128];
    float acc = bl[o];
    #pragma unroll
    for (int k4 = 0; k4 < 32; k4++) {
        float4 hv = *(const float4*)&hr[k4 * 4];
        acc += hv.x * Wl[(k4 * 4 + 0) * 8 + o];
        acc += hv.y * Wl[(k4 * 4 + 1) * 8 + o];
        acc += hv.z * Wl[(k4 * 4 + 2) * 8 + o];
        acc += hv.w * Wl[(k4 * 4 + 3) * 8 + o];
    }
    out[row * 8 + o] = acc;
}

// ---------------- launch ----------------

extern "C" void kernel_launch(void* const* d_in, const int* in_sizes, int n_in,
                              void* d_out, int out_size, void* d_ws, size_t ws_size,
                              hipStream_t stream) {
    const float* x     = (const float*)d_in[0];
    const int*   ei    = (const int*)d_in[1];
    const float* W1    = (const float*)d_in[2];
    const float* attS1 = (const float*)d_in[3];
    const float* attD1 = (const float*)d_in[4];
    const float* b1    = (const float*)d_in[5];
    const float* W2    = (const float*)d_in[6];
    const float* attS2 = (const float*)d_in[7];
    const float* attD2 = (const float*)d_in[8];
    const float* b2    = (const float*)d_in[9];
    const float* Wout  = (const float*)d_in[10];
    const float* bout  = (const float*)d_in[11];
    float* out = (float*)d_out;

    char* ws = (char*)d_ws;
    size_t off = 0;
    auto alloc = [&](size_t bytes) -> void* {
        void* p = ws + off;
        off += (bytes + 255) & ~(size_t)255;
        return p;
    };
    float* hA        = (float*)alloc((size_t)N_NODES * 128 * 4);
    float* hB        = (float*)alloc((size_t)N_NODES * 128 * 4);
    float* a_s       = (float*)alloc((size_t)N_NODES * 4 * 4);
    float* a_d       = (float*)alloc((size_t)N_NODES * 4 * 4);
    int*   deg       = (int*)alloc((size_t)N_NODES * 4);
    int*   row_start = (int*)alloc((size_t)(N_NODES + 1) * 4);
    int*   cursor    = (int*)alloc((size_t)N_NODES * 4);
    int*   part      = (int*)alloc(256 * 4);
    int*   col       = (int*)alloc((size_t)NE_TOT * 4);

    hipMemsetAsync(deg, 0, (size_t)N_NODES * 4, stream);
    int nbE = (NE_TOT + 255) / 256;
    int nbS = (N_NODES + 1023) / 1024;   // 49
    k_hist<<<nbE, 256, 0, stream>>>(ei, deg);
    k_scan1<<<nbS, 256, 0, stream>>>(deg, part);
    k_scan2<<<1, 256, 0, stream>>>(part, row_start, nbS);
    k_scan3<<<nbS, 256, 0, stream>>>(deg, part, row_start, cursor);
    k_scatter<<<nbE, 256, 0, stream>>>(ei, cursor, col);

    int nbG = (N_NODES + 31) / 32;
    int nbA = (N_NODES + 3) / 4;
    k_gemm_att<<<nbG, 256, 0, stream>>>(x, W1, attS1, attD1, hA, a_s, a_d);
    k_agg<1><<<nbA, 256, 0, stream>>>(hA, a_s, a_d, row_start, col, b1, hB);
    k_gemm_att<<<nbG, 256, 0, stream>>>(hB, W2, attS2, attD2, hA, a_s, a_d);
    k_agg<0><<<nbA, 256, 0, stream>>>(hA, a_s, a_d, row_start, col, b2, hB);

    int nbO = (N_NODES * 8 + 255) / 256;
    k_out<<<nbO, 256, 0, stream>>>(hB, Wout, bout, out);
}

// Round 3
// 476.658 us; speedup vs baseline: 1.1388x; 1.1388x over previous
//
#include <hip/hip_runtime.h>
#include <math.h>

#define N_NODES 50000
#define E_EDGES 1600000
#define NE_TOT  (E_EDGES + N_NODES)

// bucketed scatter geometry
#define BSH 7                                   // 128 nodes per bucket
#define NBKT ((N_NODES + 127) >> 7)             // 391 buckets
#define EPW 8192                                // edges per A-pass workgroup
#define NWA ((NE_TOT + EPW - 1) / EPW)          // 202 workgroups

// ---------------- degree histogram + row_start scan ----------------

__global__ void k_hist(const int* __restrict__ ei, int* __restrict__ deg) {
    int i = blockIdx.x * 256 + threadIdx.x;
    if (i < E_EDGES) {
        int d = ei[E_EDGES + i];
        atomicAdd(&deg[d], 1);
    } else if (i < NE_TOT) {
        atomicAdd(&deg[i - E_EDGES], 1);   // self loop
    }
}

__global__ void k_scan1(const int* __restrict__ deg, int* __restrict__ part) {
    __shared__ int sh[256];
    int base = blockIdx.x * 1024;
    int t = threadIdx.x;
    int s = 0;
    #pragma unroll
    for (int j = 0; j < 4; j++) {
        int i = base + t * 4 + j;
        s += (i < N_NODES) ? deg[i] : 0;
    }
    sh[t] = s; __syncthreads();
    for (int d = 128; d > 0; d >>= 1) {
        if (t < d) sh[t] += sh[t + d];
        __syncthreads();
    }
    if (t == 0) part[blockIdx.x] = sh[0];
}

__global__ void k_scan2(int* part, int* __restrict__ row_start, int nb) {
    __shared__ int sh[256];
    int t = threadIdx.x;
    int v = (t < nb) ? part[t] : 0;
    sh[t] = v; __syncthreads();
    for (int d = 1; d < 256; d <<= 1) {
        int x = (t >= d) ? sh[t - d] : 0;
        __syncthreads();
        sh[t] += x;
        __syncthreads();
    }
    if (t < nb) part[t] = sh[t] - v;       // exclusive
    if (t == 255) row_start[N_NODES] = sh[255];
}

__global__ void k_scan3(const int* __restrict__ deg, const int* __restrict__ part,
                        int* __restrict__ row_start) {
    __shared__ int sh[256];
    int base = blockIdx.x * 1024;
    int t = threadIdx.x;
    int v[4]; int ts = 0;
    #pragma unroll
    for (int j = 0; j < 4; j++) {
        int i = base + t * 4 + j;
        v[j] = (i < N_NODES) ? deg[i] : 0;
        ts += v[j];
    }
    sh[t] = ts; __syncthreads();
    for (int d = 1; d < 256; d <<= 1) {
        int x = (t >= d) ? sh[t - d] : 0;
        __syncthreads();
        sh[t] += x;
        __syncthreads();
    }
    int excl = sh[t] - ts + part[blockIdx.x];
    #pragma unroll
    for (int j = 0; j < 4; j++) {
        int i = base + t * 4 + j;
        if (i < N_NODES) { row_start[i] = excl; excl += v[j]; }
    }
}

// ---------------- bucketed edge scatter ----------------
// Pass A1: per-workgroup histogram over NBKT buckets (128 dst nodes each)

__global__ __launch_bounds__(256) void k_binhist(const int* __restrict__ ei,
                                                 int* __restrict__ histG) {
    __shared__ int h[NBKT];
    int t = threadIdx.x;
    for (int i = t; i < NBKT; i += 256) h[i] = 0;
    __syncthreads();
    int base = blockIdx.x * EPW;
    #pragma unroll 4
    for (int j = 0; j < EPW / 256; j++) {
        int e = base + t + 256 * j;
        if (e < NE_TOT) {
            int d = (e < E_EDGES) ? ei[E_EDGES + e] : (e - E_EDGES);
            atomicAdd(&h[d >> BSH], 1);
        }
    }
    __syncthreads();
    for (int i = t; i < NBKT; i += 256) histG[blockIdx.x * NBKT + i] = h[i];
}

// Pass A2: hist[wg][b] -> global stream start offsets (base = row_start[b<<BSH])

__global__ void k_binscan(int* __restrict__ histG, const int* __restrict__ row_start) {
    int b = blockIdx.x * 256 + threadIdx.x;
    if (b >= NBKT) return;
    int run = row_start[b << BSH];
    for (int w = 0; w < NWA; w++) {
        int v = histG[w * NBKT + b];
        histG[w * NBKT + b] = run;
        run += v;
    }
}

// Pass A3: append (src,dst) pairs into this wg's private per-bucket streams

__global__ __launch_bounds__(256) void k_binscatter(const int* __restrict__ ei,
                                                    const int* __restrict__ histG,
                                                    int2* __restrict__ pairs) {
    __shared__ int lofs[NBKT];
    int t = threadIdx.x;
    for (int i = t; i < NBKT; i += 256) lofs[i] = histG[blockIdx.x * NBKT + i];
    __syncthreads();
    int base = blockIdx.x * EPW;
    #pragma unroll 4
    for (int j = 0; j < EPW / 256; j++) {
        int e = base + t + 256 * j;
        if (e < NE_TOT) {
            int s, d;
            if (e < E_EDGES) { s = ei[e]; d = ei[E_EDGES + e]; }
            else             { s = d = e - E_EDGES; }
            int pos = atomicAdd(&lofs[d >> BSH], 1);
            pairs[pos] = make_int2(s, d);
        }
    }
}

// Pass B: one workgroup per bucket; scatter src into the dense col window

__global__ __launch_bounds__(256) void k_bucketsort(const int2* __restrict__ pairs,
                                                    const int* __restrict__ row_start,
                                                    int* __restrict__ col) {
    __shared__ int lcur[1 << BSH];
    int b = blockIdx.x, t = threadIdx.x;
    int nbeg = b << BSH;
    int nend = min(nbeg + (1 << BSH), N_NODES);
    if (t < (1 << BSH) && nbeg + t < N_NODES) lcur[t] = row_start[nbeg + t];
    __syncthreads();
    int ebeg = row_start[nbeg];
    int eend = row_start[nend];
    for (int j = ebeg + t; j < eend; j += 256) {
        int2 p = pairs[j];
        int pos = atomicAdd(&lcur[p.y - nbeg], 1);
        col[pos] = p.x;
    }
}

// ---------------- GEMM (128x128) + attention logits ----------------

__global__ __launch_bounds__(256) void k_gemm_att(
    const float* __restrict__ X, const float* __restrict__ W,
    const float* __restrict__ attS, const float* __restrict__ attD,
    float* __restrict__ Hout, float* __restrict__ a_s, float* __restrict__ a_d) {
    __shared__ float Wl[64 * 128];
    __shared__ float xs[32 * 64];
    int t = threadIdx.x;
    int g = t >> 5, cl = t & 31, c4 = cl * 4;
    int rowbase = blockIdx.x * 32;
    float4 acc[4];
    #pragma unroll
    for (int rr = 0; rr < 4; rr++) acc[rr] = make_float4(0.f, 0.f, 0.f, 0.f);

    for (int kp = 0; kp < 2; kp++) {
        __syncthreads();
        #pragma unroll
        for (int j = 0; j < 8; j++) {
            int f4 = t + 256 * j;
            int kk = f4 >> 5, cg = f4 & 31;
            *(float4*)&Wl[kk * 128 + cg * 4] =
                *(const float4*)&W[(kp * 64 + kk) * 128 + cg * 4];
        }
        #pragma unroll
        for (int j = 0; j < 2; j++) {
            int f4 = t + 256 * j;
            int r = f4 >> 4, k4 = f4 & 15;
            int grow = rowbase + r;
            float4 xv = make_float4(0.f, 0.f, 0.f, 0.f);
            if (grow < N_NODES) xv = *(const float4*)&X[grow * 128 + kp * 64 + k4 * 4];
            *(float4*)&xs[r * 64 + k4 * 4] = xv;
        }
        __syncthreads();
        #pragma unroll
        for (int k4 = 0; k4 < 16; k4++) {
            float4 xv[4];
            #pragma unroll
            for (int rr = 0; rr < 4; rr++)
                xv[rr] = *(float4*)&xs[(g * 4 + rr) * 64 + k4 * 4];
            #pragma unroll
            for (int kk = 0; kk < 4; kk++) {
                float4 wv = *(float4*)&Wl[(k4 * 4 + kk) * 128 + c4];
                #pragma unroll
                for (int rr = 0; rr < 4; rr++) {
                    float xc = (kk == 0) ? xv[rr].x : (kk == 1) ? xv[rr].y
                             : (kk == 2) ? xv[rr].z : xv[rr].w;
                    acc[rr].x += xc * wv.x;
                    acc[rr].y += xc * wv.y;
                    acc[rr].z += xc * wv.z;
                    acc[rr].w += xc * wv.w;
                }
            }
        }
    }

    float4 as4 = *(const float4*)&attS[c4];
    float4 ad4 = *(const float4*)&attD[c4];
    int head = cl >> 3;
    #pragma unroll
    for (int rr = 0; rr < 4; rr++) {
        int grow = rowbase + g * 4 + rr;
        float4 a = acc[rr];
        if (grow < N_NODES) *(float4*)&Hout[grow * 128 + c4] = a;
        float ps = a.x * as4.x + a.y * as4.y + a.z * as4.z + a.w * as4.w;
        float pd = a.x * ad4.x + a.y * ad4.y + a.z * ad4.z + a.w * ad4.w;
        ps += __shfl_xor(ps, 1); ps += __shfl_xor(ps, 2); ps += __shfl_xor(ps, 4);
        pd += __shfl_xor(pd, 1); pd += __shfl_xor(pd, 2); pd += __shfl_xor(pd, 4);
        if ((cl & 7) == 0 && grow < N_NODES) {
            a_s[grow * 4 + head] = ps;
            a_d[grow * 4 + head] = pd;
        }
    }
}

// ---------------- Attention aggregation ----------------

__device__ inline float sel4(float4 v, int i) {
    float r = v.x;
    if (i == 1) r = v.y;
    if (i == 2) r = v.z;
    if (i == 3) r = v.w;
    return r;
}

__device__ inline void merge1(float& m, float& s, float mo, float so) {
    float mn = fmaxf(m, mo);
    s = s * __expf(m - mn) + so * __expf(mo - mn);
    m = mn;
}

template<int DO_ELU>
__global__ __launch_bounds__(256) void k_agg(
    const float* __restrict__ Hin, const float* __restrict__ a_s,
    const float* __restrict__ a_d, const int* __restrict__ row_start,
    const int* __restrict__ col, const float* __restrict__ bias,
    float* __restrict__ Hout) {
    int wid = threadIdx.x >> 6;
    int lane = threadIdx.x & 63;
    int node = blockIdx.x * 4 + wid;
    if (node >= N_NODES) return;
    int beg = row_start[node], end = row_start[node + 1];
    float4 ad4 = *(const float4*)&a_d[node * 4];

    float4 m = make_float4(-1e30f, -1e30f, -1e30f, -1e30f);
    float4 s = make_float4(0.f, 0.f, 0.f, 0.f);
    for (int j = beg + lane; j < end; j += 64) {
        int src = col[j];
        float4 av = *(const float4*)&a_s[src * 4];
        float4 e;
        e.x = av.x + ad4.x; e.x = e.x > 0.f ? e.x : 0.2f * e.x;
        e.y = av.y + ad4.y; e.y = e.y > 0.f ? e.y : 0.2f * e.y;
        e.z = av.z + ad4.z; e.z = e.z > 0.f ? e.z : 0.2f * e.z;
        e.w = av.w + ad4.w; e.w = e.w > 0.f ? e.w : 0.2f * e.w;
        float mn;
        mn = fmaxf(m.x, e.x); s.x = s.x * __expf(m.x - mn) + __expf(e.x - mn); m.x = mn;
        mn = fmaxf(m.y, e.y); s.y = s.y * __expf(m.y - mn) + __expf(e.y - mn); m.y = mn;
        mn = fmaxf(m.z, e.z); s.z = s.z * __expf(m.z - mn) + __expf(e.z - mn); m.z = mn;
        mn = fmaxf(m.w, e.w); s.w = s.w * __expf(m.w - mn) + __expf(e.w - mn); m.w = mn;
    }
    #pragma unroll
    for (int off = 32; off > 0; off >>= 1) {
        float mo, so;
        mo = __shfl_xor(m.x, off); so = __shfl_xor(s.x, off); merge1(m.x, s.x, mo, so);
        mo = __shfl_xor(m.y, off); so = __shfl_xor(s.y, off); merge1(m.y, s.y, mo, so);
        mo = __shfl_xor(m.z, off); so = __shfl_xor(s.z, off); merge1(m.z, s.z, mo, so);
        mo = __shfl_xor(m.w, off); so = __shfl_xor(s.w, off); merge1(m.w, s.w, mo, so);
    }
    float4 inv;
    inv.x = 1.f / (s.x + 1e-16f);
    inv.y = 1.f / (s.y + 1e-16f);
    inv.z = 1.f / (s.z + 1e-16f);
    inv.w = 1.f / (s.w + 1e-16f);

    int slot = lane >> 5, cl = lane & 31, c4 = cl * 4, head = cl >> 3;
    float mh  = sel4(m, head);
    float ih  = sel4(inv, head);
    float adh = sel4(ad4, head);
    float4 acc = make_float4(0.f, 0.f, 0.f, 0.f);
    for (int j = beg + slot; j < end; j += 2) {
        int src = col[j];
        float eh = a_s[src * 4 + head] + adh;
        eh = eh > 0.f ? eh : 0.2f * eh;
        float alpha = __expf(eh - mh) * ih;
        float4 hv = *(const float4*)&Hin[src * 128 + c4];
        acc.x += alpha * hv.x;
        acc.y += alpha * hv.y;
        acc.z += alpha * hv.z;
        acc.w += alpha * hv.w;
    }
    acc.x += __shfl_xor(acc.x, 32);
    acc.y += __shfl_xor(acc.y, 32);
    acc.z += __shfl_xor(acc.z, 32);
    acc.w += __shfl_xor(acc.w, 32);
    if (slot == 0) {
        float4 bv = *(const float4*)&bias[c4];
        float4 o;
        o.x = acc.x + bv.x; o.y = acc.y + bv.y;
        o.z = acc.z + bv.z; o.w = acc.w + bv.w;
        if (DO_ELU) {
            o.x = o.x > 0.f ? o.x : expm1f(o.x);
            o.y = o.y > 0.f ? o.y : expm1f(o.y);
            o.z = o.z > 0.f ? o.z : expm1f(o.z);
            o.w = o.w > 0.f ? o.w : expm1f(o.w);
        }
        *(float4*)&Hout[node * 128 + c4] = o;
    }
}

// ---------------- Output projection [N,128]@[128,8] ----------------

__global__ __launch_bounds__(256) void k_out(
    const float* __restrict__ Hin, const float* __restrict__ Wout,
    const float* __restrict__ bout, float* __restrict__ out) {
    __shared__ float Wl[128 * 8];
    __shared__ float bl[8];
    int t = threadIdx.x;
    for (int j = t; j < 1024; j += 256) Wl[j] = Wout[j];
    if (t < 8) bl[t] = bout[t];
    __syncthreads();
    int gid = blockIdx.x * 256 + t;
    int row = gid >> 3, o = gid & 7;
    if (row >= N_NODES) return;
    const float* hr = &Hin[row * 128];
    float acc = bl[o];
    #pragma unroll
    for (int k4 = 0; k4 < 32; k4++) {
        float4 hv = *(const float4*)&hr[k4 * 4];
        acc += hv.x * Wl[(k4 * 4 + 0) * 8 + o];
        acc += hv.y * Wl[(k4 * 4 + 1) * 8 + o];
        acc += hv.z * Wl[(k4 * 4 + 2) * 8 + o];
        acc += hv.w * Wl[(k4 * 4 + 3) * 8 + o];
    }
    out[row * 8 + o] = acc;
}

// ---------------- launch ----------------

extern "C" void kernel_launch(void* const* d_in, const int* in_sizes, int n_in,
                              void* d_out, int out_size, void* d_ws, size_t ws_size,
                              hipStream_t stream) {
    const float* x     = (const float*)d_in[0];
    const int*   ei    = (const int*)d_in[1];
    const float* W1    = (const float*)d_in[2];
    const float* attS1 = (const float*)d_in[3];
    const float* attD1 = (const float*)d_in[4];
    const float* b1    = (const float*)d_in[5];
    const float* W2    = (const float*)d_in[6];
    const float* attS2 = (const float*)d_in[7];
    const float* attD2 = (const float*)d_in[8];
    const float* b2    = (const float*)d_in[9];
    const float* Wout  = (const float*)d_in[10];
    const float* bout  = (const float*)d_in[11];
    float* out = (float*)d_out;

    char* ws = (char*)d_ws;
    size_t off = 0;
    auto alloc = [&](size_t bytes) -> void* {
        void* p = ws + off;
        off += (bytes + 255) & ~(size_t)255;
        return p;
    };
    float* hA        = (float*)alloc((size_t)N_NODES * 128 * 4);
    float* hB        = (float*)alloc((size_t)N_NODES * 128 * 4);
    float* a_s       = (float*)alloc((size_t)N_NODES * 4 * 4);
    float* a_d       = (float*)alloc((size_t)N_NODES * 4 * 4);
    int*   deg       = (int*)alloc((size_t)N_NODES * 4);
    int*   row_start = (int*)alloc((size_t)(N_NODES + 1) * 4);
    int*   part      = (int*)alloc(256 * 4);
    int*   col       = (int*)alloc((size_t)NE_TOT * 4);
    int*   histG     = (int*)alloc((size_t)NWA * NBKT * 4);
    int2*  pairs     = (int2*)hB;   // alias: hB not live during CSR build

    hipMemsetAsync(deg, 0, (size_t)N_NODES * 4, stream);
    int nbE = (NE_TOT + 255) / 256;
    int nbS = (N_NODES + 1023) / 1024;   // 49
    k_hist<<<nbE, 256, 0, stream>>>(ei, deg);
    k_scan1<<<nbS, 256, 0, stream>>>(deg, part);
    k_scan2<<<1, 256, 0, stream>>>(part, row_start, nbS);
    k_scan3<<<nbS, 256, 0, stream>>>(deg, part, row_start);

    k_binhist<<<NWA, 256, 0, stream>>>(ei, histG);
    k_binscan<<<(NBKT + 255) / 256, 256, 0, stream>>>(histG, row_start);
    k_binscatter<<<NWA, 256, 0, stream>>>(ei, histG, pairs);
    k_bucketsort<<<NBKT, 256, 0, stream>>>(pairs, row_start, col);

    int nbG = (N_NODES + 31) / 32;
    int nbA = (N_NODES + 3) / 4;
    k_gemm_att<<<nbG, 256, 0, stream>>>(x, W1, attS1, attD1, hA, a_s, a_d);
    k_agg<1><<<nbA, 256, 0, stream>>>(hA, a_s, a_d, row_start, col, b1, hB);
    k_gemm_att<<<nbG, 256, 0, stream>>>(hB, W2, attS2, attD2, hA, a_s, a_d);
    k_agg<0><<<nbA, 256, 0, stream>>>(hA, a_s, a_d, row_start, col, b2, hB);

    int nbO = (N_NODES * 8 + 255) / 256;
    k_out<<<nbO, 256, 0, stream>>>(hB, Wout, bout, out);
}

// Round 4
// 448.926 us; speedup vs baseline: 1.2091x; 1.0618x over previous
//
#include <hip/hip_runtime.h>
#include <math.h>

#define N_NODES 50000
#define E_EDGES 1600000
#define NE_TOT  (E_EDGES + N_NODES)

// bucketed scatter geometry
#define BSH 7                                   // 128 nodes per bucket
#define NBKT ((N_NODES + 127) >> 7)             // 391 buckets
#define EPW 8192                                // edges per A-pass workgroup
#define NWA ((NE_TOT + EPW - 1) / EPW)          // 202 workgroups

#define CH 128                                  // staged edges per node chunk

// ---------------- degree histogram + row_start scan ----------------

__global__ void k_hist(const int* __restrict__ ei, int* __restrict__ deg) {
    int i = blockIdx.x * 256 + threadIdx.x;
    if (i < E_EDGES) {
        int d = ei[E_EDGES + i];
        atomicAdd(&deg[d], 1);
    } else if (i < NE_TOT) {
        atomicAdd(&deg[i - E_EDGES], 1);   // self loop
    }
}

__global__ void k_scan1(const int* __restrict__ deg, int* __restrict__ part) {
    __shared__ int sh[256];
    int base = blockIdx.x * 1024;
    int t = threadIdx.x;
    int s = 0;
    #pragma unroll
    for (int j = 0; j < 4; j++) {
        int i = base + t * 4 + j;
        s += (i < N_NODES) ? deg[i] : 0;
    }
    sh[t] = s; __syncthreads();
    for (int d = 128; d > 0; d >>= 1) {
        if (t < d) sh[t] += sh[t + d];
        __syncthreads();
    }
    if (t == 0) part[blockIdx.x] = sh[0];
}

__global__ void k_scan2(int* part, int* __restrict__ row_start, int nb) {
    __shared__ int sh[256];
    int t = threadIdx.x;
    int v = (t < nb) ? part[t] : 0;
    sh[t] = v; __syncthreads();
    for (int d = 1; d < 256; d <<= 1) {
        int x = (t >= d) ? sh[t - d] : 0;
        __syncthreads();
        sh[t] += x;
        __syncthreads();
    }
    if (t < nb) part[t] = sh[t] - v;       // exclusive
    if (t == 255) row_start[N_NODES] = sh[255];
}

__global__ void k_scan3(const int* __restrict__ deg, const int* __restrict__ part,
                        int* __restrict__ row_start) {
    __shared__ int sh[256];
    int base = blockIdx.x * 1024;
    int t = threadIdx.x;
    int v[4]; int ts = 0;
    #pragma unroll
    for (int j = 0; j < 4; j++) {
        int i = base + t * 4 + j;
        v[j] = (i < N_NODES) ? deg[i] : 0;
        ts += v[j];
    }
    sh[t] = ts; __syncthreads();
    for (int d = 1; d < 256; d <<= 1) {
        int x = (t >= d) ? sh[t - d] : 0;
        __syncthreads();
        sh[t] += x;
        __syncthreads();
    }
    int excl = sh[t] - ts + part[blockIdx.x];
    #pragma unroll
    for (int j = 0; j < 4; j++) {
        int i = base + t * 4 + j;
        if (i < N_NODES) { row_start[i] = excl; excl += v[j]; }
    }
}

// ---------------- bucketed edge scatter ----------------

__global__ __launch_bounds__(256) void k_binhist(const int* __restrict__ ei,
                                                 int* __restrict__ histG) {
    __shared__ int h[NBKT];
    int t = threadIdx.x;
    for (int i = t; i < NBKT; i += 256) h[i] = 0;
    __syncthreads();
    int base = blockIdx.x * EPW;
    #pragma unroll 4
    for (int j = 0; j < EPW / 256; j++) {
        int e = base + t + 256 * j;
        if (e < NE_TOT) {
            int d = (e < E_EDGES) ? ei[E_EDGES + e] : (e - E_EDGES);
            atomicAdd(&h[d >> BSH], 1);
        }
    }
    __syncthreads();
    for (int i = t; i < NBKT; i += 256) histG[blockIdx.x * NBKT + i] = h[i];
}

__global__ void k_binscan(int* __restrict__ histG, const int* __restrict__ row_start) {
    int b = blockIdx.x * 256 + threadIdx.x;
    if (b >= NBKT) return;
    int run = row_start[b << BSH];
    for (int w = 0; w < NWA; w++) {
        int v = histG[w * NBKT + b];
        histG[w * NBKT + b] = run;
        run += v;
    }
}

__global__ __launch_bounds__(256) void k_binscatter(const int* __restrict__ ei,
                                                    const int* __restrict__ histG,
                                                    int2* __restrict__ pairs) {
    __shared__ int lofs[NBKT];
    int t = threadIdx.x;
    for (int i = t; i < NBKT; i += 256) lofs[i] = histG[blockIdx.x * NBKT + i];
    __syncthreads();
    int base = blockIdx.x * EPW;
    #pragma unroll 4
    for (int j = 0; j < EPW / 256; j++) {
        int e = base + t + 256 * j;
        if (e < NE_TOT) {
            int s, d;
            if (e < E_EDGES) { s = ei[e]; d = ei[E_EDGES + e]; }
            else             { s = d = e - E_EDGES; }
            int pos = atomicAdd(&lofs[d >> BSH], 1);
            pairs[pos] = make_int2(s, d);
        }
    }
}

__global__ __launch_bounds__(256) void k_bucketsort(const int2* __restrict__ pairs,
                                                    const int* __restrict__ row_start,
                                                    int* __restrict__ col) {
    __shared__ int lcur[1 << BSH];
    int b = blockIdx.x, t = threadIdx.x;
    int nbeg = b << BSH;
    int nend = min(nbeg + (1 << BSH), N_NODES);
    if (t < (1 << BSH) && nbeg + t < N_NODES) lcur[t] = row_start[nbeg + t];
    __syncthreads();
    int ebeg = row_start[nbeg];
    int eend = row_start[nend];
    for (int j = ebeg + t; j < eend; j += 256) {
        int2 p = pairs[j];
        int pos = atomicAdd(&lcur[p.y - nbeg], 1);
        col[pos] = p.x;
    }
}

// ---------------- GEMM (128x128) + attention logits ----------------

__global__ __launch_bounds__(256) void k_gemm_att(
    const float* __restrict__ X, const float* __restrict__ W,
    const float* __restrict__ attS, const float* __restrict__ attD,
    float* __restrict__ Hout, float* __restrict__ a_s, float* __restrict__ a_d) {
    __shared__ float Wl[64 * 128];
    __shared__ float xs[32 * 64];
    int t = threadIdx.x;
    int g = t >> 5, cl = t & 31, c4 = cl * 4;
    int rowbase = blockIdx.x * 32;
    float4 acc[4];
    #pragma unroll
    for (int rr = 0; rr < 4; rr++) acc[rr] = make_float4(0.f, 0.f, 0.f, 0.f);

    for (int kp = 0; kp < 2; kp++) {
        __syncthreads();
        #pragma unroll
        for (int j = 0; j < 8; j++) {
            int f4 = t + 256 * j;
            int kk = f4 >> 5, cg = f4 & 31;
            *(float4*)&Wl[kk * 128 + cg * 4] =
                *(const float4*)&W[(kp * 64 + kk) * 128 + cg * 4];
        }
        #pragma unroll
        for (int j = 0; j < 2; j++) {
            int f4 = t + 256 * j;
            int r = f4 >> 4, k4 = f4 & 15;
            int grow = rowbase + r;
            float4 xv = make_float4(0.f, 0.f, 0.f, 0.f);
            if (grow < N_NODES) xv = *(const float4*)&X[grow * 128 + kp * 64 + k4 * 4];
            *(float4*)&xs[r * 64 + k4 * 4] = xv;
        }
        __syncthreads();
        #pragma unroll
        for (int k4 = 0; k4 < 16; k4++) {
            float4 xv[4];
            #pragma unroll
            for (int rr = 0; rr < 4; rr++)
                xv[rr] = *(float4*)&xs[(g * 4 + rr) * 64 + k4 * 4];
            #pragma unroll
            for (int kk = 0; kk < 4; kk++) {
                float4 wv = *(float4*)&Wl[(k4 * 4 + kk) * 128 + c4];
                #pragma unroll
                for (int rr = 0; rr < 4; rr++) {
                    float xc = (kk == 0) ? xv[rr].x : (kk == 1) ? xv[rr].y
                             : (kk == 2) ? xv[rr].z : xv[rr].w;
                    acc[rr].x += xc * wv.x;
                    acc[rr].y += xc * wv.y;
                    acc[rr].z += xc * wv.z;
                    acc[rr].w += xc * wv.w;
                }
            }
        }
    }

    float4 as4 = *(const float4*)&attS[c4];
    float4 ad4 = *(const float4*)&attD[c4];
    int head = cl >> 3;
    #pragma unroll
    for (int rr = 0; rr < 4; rr++) {
        int grow = rowbase + g * 4 + rr;
        float4 a = acc[rr];
        if (grow < N_NODES) *(float4*)&Hout[grow * 128 + c4] = a;
        float ps = a.x * as4.x + a.y * as4.y + a.z * as4.z + a.w * as4.w;
        float pd = a.x * ad4.x + a.y * ad4.y + a.z * ad4.z + a.w * ad4.w;
        ps += __shfl_xor(ps, 1); ps += __shfl_xor(ps, 2); ps += __shfl_xor(ps, 4);
        pd += __shfl_xor(pd, 1); pd += __shfl_xor(pd, 2); pd += __shfl_xor(pd, 4);
        if ((cl & 7) == 0 && grow < N_NODES) {
            a_s[grow * 4 + head] = ps;
            a_d[grow * 4 + head] = pd;
        }
    }
}

// ---------------- Attention aggregation ----------------

__device__ inline float sel4(float4 v, int i) {
    float r = v.x;
    if (i == 1) r = v.y;
    if (i == 2) r = v.z;
    if (i == 3) r = v.w;
    return r;
}

__device__ inline float4 leaky4(float4 a, float4 b) {
    float4 e;
    e.x = a.x + b.x; e.x = e.x > 0.f ? e.x : 0.2f * e.x;
    e.y = a.y + b.y; e.y = e.y > 0.f ? e.y : 0.2f * e.y;
    e.z = a.z + b.z; e.z = e.z > 0.f ? e.z : 0.2f * e.z;
    e.w = a.w + b.w; e.w = e.w > 0.f ? e.w : 0.2f * e.w;
    return e;
}

template<int DO_ELU>
__global__ __launch_bounds__(256) void k_agg(
    const float* __restrict__ Hin, const float* __restrict__ a_s,
    const float* __restrict__ a_d, const int* __restrict__ row_start,
    const int* __restrict__ col, const float* __restrict__ bias,
    float* __restrict__ Hout) {
    __shared__ float4 eS[4][CH];    // staged e -> p per wave
    __shared__ int    sS[4][CH];    // staged src per wave

    int wid = threadIdx.x >> 6;
    int lane = threadIdx.x & 63;
    int node = blockIdx.x * 4 + wid;
    if (node >= N_NODES) return;
    int beg = row_start[node], end = row_start[node + 1];
    int deg = end - beg;
    float4 ad4 = *(const float4*)&a_d[node * 4];
    float4* eA = eS[wid];
    int*    srcA = sS[wid];

    // pass 1: stage {src, e4} for first CH edges, track running max only
    float4 m = make_float4(-1e30f, -1e30f, -1e30f, -1e30f);
    for (int j = beg + lane; j < end; j += 64) {
        int src = col[j];
        float4 av = *(const float4*)&a_s[src * 4];
        float4 e = leaky4(av, ad4);
        int idx = j - beg;
        if (idx < CH) { srcA[idx] = src; eA[idx] = e; }
        m.x = fmaxf(m.x, e.x); m.y = fmaxf(m.y, e.y);
        m.z = fmaxf(m.z, e.z); m.w = fmaxf(m.w, e.w);
    }
    #pragma unroll
    for (int off = 32; off > 0; off >>= 1) {
        m.x = fmaxf(m.x, __shfl_xor(m.x, off));
        m.y = fmaxf(m.y, __shfl_xor(m.y, off));
        m.z = fmaxf(m.z, __shfl_xor(m.z, off));
        m.w = fmaxf(m.w, __shfl_xor(m.w, off));
    }

    // convert staged e -> p = exp(e-m), accumulate partial denom
    float4 s = make_float4(0.f, 0.f, 0.f, 0.f);
    int nst = min(deg, CH);
    for (int idx = lane; idx < nst; idx += 64) {
        float4 e = eA[idx];
        float4 p;
        p.x = __expf(e.x - m.x); p.y = __expf(e.y - m.y);
        p.z = __expf(e.z - m.z); p.w = __expf(e.w - m.w);
        s.x += p.x; s.y += p.y; s.z += p.z; s.w += p.w;
        eA[idx] = p;
    }
    // tail edges beyond CH (rare): recompute for denom
    for (int j = beg + CH + lane; j < end; j += 64) {
        int src = col[j];
        float4 av = *(const float4*)&a_s[src * 4];
        float4 e = leaky4(av, ad4);
        s.x += __expf(e.x - m.x); s.y += __expf(e.y - m.y);
        s.z += __expf(e.z - m.z); s.w += __expf(e.w - m.w);
    }
    #pragma unroll
    for (int off = 32; off > 0; off >>= 1) {
        s.x += __shfl_xor(s.x, off);
        s.y += __shfl_xor(s.y, off);
        s.z += __shfl_xor(s.z, off);
        s.w += __shfl_xor(s.w, off);
    }
    float4 inv;
    inv.x = 1.f / (s.x + 1e-16f);
    inv.y = 1.f / (s.y + 1e-16f);
    inv.z = 1.f / (s.z + 1e-16f);
    inv.w = 1.f / (s.w + 1e-16f);

    // consume: 2 edge slots x 32 channel-lanes; denom folded into final scale
    int slot = lane >> 5, cl = lane & 31, c4 = cl * 4, head = cl >> 3;
    const float* hbase = Hin + c4;
    const float* pA = (const float*)eA;
    float4 acc = make_float4(0.f, 0.f, 0.f, 0.f);
    #pragma unroll 4
    for (int i = slot; i < nst; i += 2) {
        int src = srcA[i];
        float p = pA[i * 4 + head];
        float4 hv = *(const float4*)(hbase + (size_t)src * 128);
        acc.x += p * hv.x; acc.y += p * hv.y;
        acc.z += p * hv.z; acc.w += p * hv.w;
    }
    // overflow chunks (deg > CH, rare): restage then consume
    for (int cb = beg + CH; cb < end; cb += CH) {
        int cnt = min(end - cb, CH);
        for (int idx = lane; idx < cnt; idx += 64) {
            int src = col[cb + idx];
            float4 av = *(const float4*)&a_s[src * 4];
            float4 e = leaky4(av, ad4);
            float4 p;
            p.x = __expf(e.x - m.x); p.y = __expf(e.y - m.y);
            p.z = __expf(e.z - m.z); p.w = __expf(e.w - m.w);
            srcA[idx] = src; eA[idx] = p;
        }
        #pragma unroll 4
        for (int i = slot; i < cnt; i += 2) {
            int src = srcA[i];
            float p = pA[i * 4 + head];
            float4 hv = *(const float4*)(hbase + (size_t)src * 128);
            acc.x += p * hv.x; acc.y += p * hv.y;
            acc.z += p * hv.z; acc.w += p * hv.w;
        }
    }

    acc.x += __shfl_xor(acc.x, 32);
    acc.y += __shfl_xor(acc.y, 32);
    acc.z += __shfl_xor(acc.z, 32);
    acc.w += __shfl_xor(acc.w, 32);
    if (slot == 0) {
        float ih = sel4(inv, head);
        float4 bv = *(const float4*)&bias[c4];
        float4 o;
        o.x = acc.x * ih + bv.x; o.y = acc.y * ih + bv.y;
        o.z = acc.z * ih + bv.z; o.w = acc.w * ih + bv.w;
        if (DO_ELU) {
            o.x = o.x > 0.f ? o.x : expm1f(o.x);
            o.y = o.y > 0.f ? o.y : expm1f(o.y);
            o.z = o.z > 0.f ? o.z : expm1f(o.z);
            o.w = o.w > 0.f ? o.w : expm1f(o.w);
        }
        *(float4*)&Hout[node * 128 + c4] = o;
    }
}

// ---------------- Output projection [N,128]@[128,8] ----------------

__global__ __launch_bounds__(256) void k_out(
    const float* __restrict__ Hin, const float* __restrict__ Wout,
    const float* __restrict__ bout, float* __restrict__ out) {
    __shared__ float Wl[128 * 8];
    __shared__ float bl[8];
    int t = threadIdx.x;
    for (int j = t; j < 1024; j += 256) Wl[j] = Wout[j];
    if (t < 8) bl[t] = bout[t];
    __syncthreads();
    int gid = blockIdx.x * 256 + t;
    int row = gid >> 3, o = gid & 7;
    if (row >= N_NODES) return;
    const float* hr = &Hin[row * 128];
    float acc = bl[o];
    #pragma unroll
    for (int k4 = 0; k4 < 32; k4++) {
        float4 hv = *(const float4*)&hr[k4 * 4];
        acc += hv.x * Wl[(k4 * 4 + 0) * 8 + o];
        acc += hv.y * Wl[(k4 * 4 + 1) * 8 + o];
        acc += hv.z * Wl[(k4 * 4 + 2) * 8 + o];
        acc += hv.w * Wl[(k4 * 4 + 3) * 8 + o];
    }
    out[row * 8 + o] = acc;
}

// ---------------- launch ----------------

extern "C" void kernel_launch(void* const* d_in, const int* in_sizes, int n_in,
                              void* d_out, int out_size, void* d_ws, size_t ws_size,
                              hipStream_t stream) {
    const float* x     = (const float*)d_in[0];
    const int*   ei    = (const int*)d_in[1];
    const float* W1    = (const float*)d_in[2];
    const float* attS1 = (const float*)d_in[3];
    const float* attD1 = (const float*)d_in[4];
    const float* b1    = (const float*)d_in[5];
    const float* W2    = (const float*)d_in[6];
    const float* attS2 = (const float*)d_in[7];
    const float* attD2 = (const float*)d_in[8];
    const float* b2    = (const float*)d_in[9];
    const float* Wout  = (const float*)d_in[10];
    const float* bout  = (const float*)d_in[11];
    float* out = (float*)d_out;

    char* ws = (char*)d_ws;
    size_t off = 0;
    auto alloc = [&](size_t bytes) -> void* {
        void* p = ws + off;
        off += (bytes + 255) & ~(size_t)255;
        return p;
    };
    float* hA        = (float*)alloc((size_t)N_NODES * 128 * 4);
    float* hB        = (float*)alloc((size_t)N_NODES * 128 * 4);
    float* a_s       = (float*)alloc((size_t)N_NODES * 4 * 4);
    float* a_d       = (float*)alloc((size_t)N_NODES * 4 * 4);
    int*   deg       = (int*)alloc((size_t)N_NODES * 4);
    int*   row_start = (int*)alloc((size_t)(N_NODES + 1) * 4);
    int*   part      = (int*)alloc(256 * 4);
    int*   col       = (int*)alloc((size_t)NE_TOT * 4);
    int*   histG     = (int*)alloc((size_t)NWA * NBKT * 4);
    int2*  pairs     = (int2*)hB;   // alias: hB not live during CSR build

    hipMemsetAsync(deg, 0, (size_t)N_NODES * 4, stream);
    int nbE = (NE_TOT + 255) / 256;
    int nbS = (N_NODES + 1023) / 1024;   // 49
    k_hist<<<nbE, 256, 0, stream>>>(ei, deg);
    k_scan1<<<nbS, 256, 0, stream>>>(deg, part);
    k_scan2<<<1, 256, 0, stream>>>(part, row_start, nbS);
    k_scan3<<<nbS, 256, 0, stream>>>(deg, part, row_start);

    k_binhist<<<NWA, 256, 0, stream>>>(ei, histG);
    k_binscan<<<(NBKT + 255) / 256, 256, 0, stream>>>(histG, row_start);
    k_binscatter<<<NWA, 256, 0, stream>>>(ei, histG, pairs);
    k_bucketsort<<<NBKT, 256, 0, stream>>>(pairs, row_start, col);

    int nbG = (N_NODES + 31) / 32;
    int nbA = (N_NODES + 3) / 4;
    k_gemm_att<<<nbG, 256, 0, stream>>>(x, W1, attS1, attD1, hA, a_s, a_d);
    k_agg<1><<<nbA, 256, 0, stream>>>(hA, a_s, a_d, row_start, col, b1, hB);
    k_gemm_att<<<nbG, 256, 0, stream>>>(hB, W2, attS2, attD2, hA, a_s, a_d);
    k_agg<0><<<nbA, 256, 0, stream>>>(hA, a_s, a_d, row_start, col, b2, hB);

    int nbO = (N_NODES * 8 + 255) / 256;
    k_out<<<nbO, 256, 0, stream>>>(hB, Wout, bout, out);
}

// Round 5
// 371.054 us; speedup vs baseline: 1.4629x; 1.2099x over previous
//
#include <hip/hip_runtime.h>
#include <hip/hip_fp16.h>
#include <math.h>

#define N_NODES 50000
#define E_EDGES 1600000
#define NE_TOT  (E_EDGES + N_NODES)

// bucketed scatter geometry
#define BSH 7                                   // 128 nodes per bucket
#define NBKT ((N_NODES + 127) >> 7)             // 391 buckets
#define EPW 8192                                // edges per A-pass workgroup
#define NWA ((NE_TOT + EPW - 1) / EPW)          // 202 workgroups

#define CH 128                                  // staged edges per node chunk

// ---------------- degree histogram + row_start scan ----------------

__global__ void k_hist(const int* __restrict__ ei, int* __restrict__ deg) {
    int i = blockIdx.x * 256 + threadIdx.x;
    if (i < E_EDGES) {
        int d = ei[E_EDGES + i];
        atomicAdd(&deg[d], 1);
    } else if (i < NE_TOT) {
        atomicAdd(&deg[i - E_EDGES], 1);   // self loop
    }
}

__global__ void k_scan1(const int* __restrict__ deg, int* __restrict__ part) {
    __shared__ int sh[256];
    int base = blockIdx.x * 1024;
    int t = threadIdx.x;
    int s = 0;
    #pragma unroll
    for (int j = 0; j < 4; j++) {
        int i = base + t * 4 + j;
        s += (i < N_NODES) ? deg[i] : 0;
    }
    sh[t] = s; __syncthreads();
    for (int d = 128; d > 0; d >>= 1) {
        if (t < d) sh[t] += sh[t + d];
        __syncthreads();
    }
    if (t == 0) part[blockIdx.x] = sh[0];
}

__global__ void k_scan2(int* part, int* __restrict__ row_start, int nb) {
    __shared__ int sh[256];
    int t = threadIdx.x;
    int v = (t < nb) ? part[t] : 0;
    sh[t] = v; __syncthreads();
    for (int d = 1; d < 256; d <<= 1) {
        int x = (t >= d) ? sh[t - d] : 0;
        __syncthreads();
        sh[t] += x;
        __syncthreads();
    }
    if (t < nb) part[t] = sh[t] - v;       // exclusive
    if (t == 255) row_start[N_NODES] = sh[255];
}

__global__ void k_scan3(const int* __restrict__ deg, const int* __restrict__ part,
                        int* __restrict__ row_start) {
    __shared__ int sh[256];
    int base = blockIdx.x * 1024;
    int t = threadIdx.x;
    int v[4]; int ts = 0;
    #pragma unroll
    for (int j = 0; j < 4; j++) {
        int i = base + t * 4 + j;
        v[j] = (i < N_NODES) ? deg[i] : 0;
        ts += v[j];
    }
    sh[t] = ts; __syncthreads();
    for (int d = 1; d < 256; d <<= 1) {
        int x = (t >= d) ? sh[t - d] : 0;
        __syncthreads();
        sh[t] += x;
        __syncthreads();
    }
    int excl = sh[t] - ts + part[blockIdx.x];
    #pragma unroll
    for (int j = 0; j < 4; j++) {
        int i = base + t * 4 + j;
        if (i < N_NODES) { row_start[i] = excl; excl += v[j]; }
    }
}

// ---------------- bucketed edge scatter ----------------

__global__ __launch_bounds__(256) void k_binhist(const int* __restrict__ ei,
                                                 int* __restrict__ histG) {
    __shared__ int h[NBKT];
    int t = threadIdx.x;
    for (int i = t; i < NBKT; i += 256) h[i] = 0;
    __syncthreads();
    int base = blockIdx.x * EPW;
    #pragma unroll 4
    for (int j = 0; j < EPW / 256; j++) {
        int e = base + t + 256 * j;
        if (e < NE_TOT) {
            int d = (e < E_EDGES) ? ei[E_EDGES + e] : (e - E_EDGES);
            atomicAdd(&h[d >> BSH], 1);
        }
    }
    __syncthreads();
    for (int i = t; i < NBKT; i += 256) histG[blockIdx.x * NBKT + i] = h[i];
}

__global__ void k_binscan(int* __restrict__ histG, const int* __restrict__ row_start) {
    int b = blockIdx.x * 256 + threadIdx.x;
    if (b >= NBKT) return;
    int run = row_start[b << BSH];
    for (int w = 0; w < NWA; w++) {
        int v = histG[w * NBKT + b];
        histG[w * NBKT + b] = run;
        run += v;
    }
}

__global__ __launch_bounds__(256) void k_binscatter(const int* __restrict__ ei,
                                                    const int* __restrict__ histG,
                                                    int2* __restrict__ pairs) {
    __shared__ int lofs[NBKT];
    int t = threadIdx.x;
    for (int i = t; i < NBKT; i += 256) lofs[i] = histG[blockIdx.x * NBKT + i];
    __syncthreads();
    int base = blockIdx.x * EPW;
    #pragma unroll 4
    for (int j = 0; j < EPW / 256; j++) {
        int e = base + t + 256 * j;
        if (e < NE_TOT) {
            int s, d;
            if (e < E_EDGES) { s = ei[e]; d = ei[E_EDGES + e]; }
            else             { s = d = e - E_EDGES; }
            int pos = atomicAdd(&lofs[d >> BSH], 1);
            pairs[pos] = make_int2(s, d);
        }
    }
}

__global__ __launch_bounds__(256) void k_bucketsort(const int2* __restrict__ pairs,
                                                    const int* __restrict__ row_start,
                                                    int* __restrict__ col) {
    __shared__ int lcur[1 << BSH];
    int b = blockIdx.x, t = threadIdx.x;
    int nbeg = b << BSH;
    int nend = min(nbeg + (1 << BSH), N_NODES);
    if (t < (1 << BSH) && nbeg + t < N_NODES) lcur[t] = row_start[nbeg + t];
    __syncthreads();
    int ebeg = row_start[nbeg];
    int eend = row_start[nend];
    for (int j = ebeg + t; j < eend; j += 256) {
        int2 p = pairs[j];
        int pos = atomicAdd(&lcur[p.y - nbeg], 1);
        col[pos] = p.x;
    }
}

// ---------------- GEMM (128x128) + attention logits ----------------
// writes h only as fp16 (gather copy); logits computed fp32 in epilogue

__global__ __launch_bounds__(256) void k_gemm_att(
    const float* __restrict__ X, const float* __restrict__ W,
    const float* __restrict__ attS, const float* __restrict__ attD,
    __half* __restrict__ H16, float* __restrict__ a_s, float* __restrict__ a_d) {
    __shared__ float Wl[64 * 128];
    __shared__ float xs[32 * 64];
    int t = threadIdx.x;
    int g = t >> 5, cl = t & 31, c4 = cl * 4;
    int rowbase = blockIdx.x * 32;
    float4 acc[4];
    #pragma unroll
    for (int rr = 0; rr < 4; rr++) acc[rr] = make_float4(0.f, 0.f, 0.f, 0.f);

    for (int kp = 0; kp < 2; kp++) {
        __syncthreads();
        #pragma unroll
        for (int j = 0; j < 8; j++) {
            int f4 = t + 256 * j;
            int kk = f4 >> 5, cg = f4 & 31;
            *(float4*)&Wl[kk * 128 + cg * 4] =
                *(const float4*)&W[(kp * 64 + kk) * 128 + cg * 4];
        }
        #pragma unroll
        for (int j = 0; j < 2; j++) {
            int f4 = t + 256 * j;
            int r = f4 >> 4, k4 = f4 & 15;
            int grow = rowbase + r;
            float4 xv = make_float4(0.f, 0.f, 0.f, 0.f);
            if (grow < N_NODES) xv = *(const float4*)&X[grow * 128 + kp * 64 + k4 * 4];
            *(float4*)&xs[r * 64 + k4 * 4] = xv;
        }
        __syncthreads();
        #pragma unroll
        for (int k4 = 0; k4 < 16; k4++) {
            float4 xv[4];
            #pragma unroll
            for (int rr = 0; rr < 4; rr++)
                xv[rr] = *(float4*)&xs[(g * 4 + rr) * 64 + k4 * 4];
            #pragma unroll
            for (int kk = 0; kk < 4; kk++) {
                float4 wv = *(float4*)&Wl[(k4 * 4 + kk) * 128 + c4];
                #pragma unroll
                for (int rr = 0; rr < 4; rr++) {
                    float xc = (kk == 0) ? xv[rr].x : (kk == 1) ? xv[rr].y
                             : (kk == 2) ? xv[rr].z : xv[rr].w;
                    acc[rr].x += xc * wv.x;
                    acc[rr].y += xc * wv.y;
                    acc[rr].z += xc * wv.z;
                    acc[rr].w += xc * wv.w;
                }
            }
        }
    }

    float4 as4 = *(const float4*)&attS[c4];
    float4 ad4 = *(const float4*)&attD[c4];
    int head = cl >> 3;
    #pragma unroll
    for (int rr = 0; rr < 4; rr++) {
        int grow = rowbase + g * 4 + rr;
        float4 a = acc[rr];
        if (grow < N_NODES) {
            __half2 lo = __floats2half2_rn(a.x, a.y);
            __half2 hi = __floats2half2_rn(a.z, a.w);
            uint2 pk;
            pk.x = *(unsigned int*)&lo;
            pk.y = *(unsigned int*)&hi;
            *(uint2*)&H16[(size_t)grow * 128 + c4] = pk;
        }
        float ps = a.x * as4.x + a.y * as4.y + a.z * as4.z + a.w * as4.w;
        float pd = a.x * ad4.x + a.y * ad4.y + a.z * ad4.z + a.w * ad4.w;
        ps += __shfl_xor(ps, 1); ps += __shfl_xor(ps, 2); ps += __shfl_xor(ps, 4);
        pd += __shfl_xor(pd, 1); pd += __shfl_xor(pd, 2); pd += __shfl_xor(pd, 4);
        if ((cl & 7) == 0 && grow < N_NODES) {
            a_s[grow * 4 + head] = ps;
            a_d[grow * 4 + head] = pd;
        }
    }
}

// ---------------- Attention aggregation ----------------

__device__ inline float sel4(float4 v, int i) {
    float r = v.x;
    if (i == 1) r = v.y;
    if (i == 2) r = v.z;
    if (i == 3) r = v.w;
    return r;
}

__device__ inline float4 leaky4(float4 a, float4 b) {
    float4 e;
    e.x = a.x + b.x; e.x = e.x > 0.f ? e.x : 0.2f * e.x;
    e.y = a.y + b.y; e.y = e.y > 0.f ? e.y : 0.2f * e.y;
    e.z = a.z + b.z; e.z = e.z > 0.f ? e.z : 0.2f * e.z;
    e.w = a.w + b.w; e.w = e.w > 0.f ? e.w : 0.2f * e.w;
    return e;
}

template<int DO_ELU>
__global__ __launch_bounds__(256) void k_agg(
    const __half* __restrict__ H16, const float* __restrict__ a_s,
    const float* __restrict__ a_d, const int* __restrict__ row_start,
    const int* __restrict__ col, const float* __restrict__ bias,
    float* __restrict__ Hout) {
    __shared__ float4 eS[4][CH];    // staged e -> p per wave
    __shared__ int    sS[4][CH];    // staged src per wave

    int wid = threadIdx.x >> 6;
    int lane = threadIdx.x & 63;
    int node = blockIdx.x * 4 + wid;
    if (node >= N_NODES) return;
    int beg = row_start[node], end = row_start[node + 1];
    int deg = end - beg;
    float4 ad4 = *(const float4*)&a_d[node * 4];
    float4* eA = eS[wid];
    int*    srcA = sS[wid];

    // pass 1: stage {src, e4} for first CH edges, track running max only
    float4 m = make_float4(-1e30f, -1e30f, -1e30f, -1e30f);
    for (int j = beg + lane; j < end; j += 64) {
        int src = col[j];
        float4 av = *(const float4*)&a_s[src * 4];
        float4 e = leaky4(av, ad4);
        int idx = j - beg;
        if (idx < CH) { srcA[idx] = src; eA[idx] = e; }
        m.x = fmaxf(m.x, e.x); m.y = fmaxf(m.y, e.y);
        m.z = fmaxf(m.z, e.z); m.w = fmaxf(m.w, e.w);
    }
    #pragma unroll
    for (int off = 32; off > 0; off >>= 1) {
        m.x = fmaxf(m.x, __shfl_xor(m.x, off));
        m.y = fmaxf(m.y, __shfl_xor(m.y, off));
        m.z = fmaxf(m.z, __shfl_xor(m.z, off));
        m.w = fmaxf(m.w, __shfl_xor(m.w, off));
    }

    // convert staged e -> p = exp(e-m), accumulate partial denom
    float4 s = make_float4(0.f, 0.f, 0.f, 0.f);
    int nst = min(deg, CH);
    for (int idx = lane; idx < nst; idx += 64) {
        float4 e = eA[idx];
        float4 p;
        p.x = __expf(e.x - m.x); p.y = __expf(e.y - m.y);
        p.z = __expf(e.z - m.z); p.w = __expf(e.w - m.w);
        s.x += p.x; s.y += p.y; s.z += p.z; s.w += p.w;
        eA[idx] = p;
    }
    // tail edges beyond CH (rare): recompute for denom
    for (int j = beg + CH + lane; j < end; j += 64) {
        int src = col[j];
        float4 av = *(const float4*)&a_s[src * 4];
        float4 e = leaky4(av, ad4);
        s.x += __expf(e.x - m.x); s.y += __expf(e.y - m.y);
        s.z += __expf(e.z - m.z); s.w += __expf(e.w - m.w);
    }
    #pragma unroll
    for (int off = 32; off > 0; off >>= 1) {
        s.x += __shfl_xor(s.x, off);
        s.y += __shfl_xor(s.y, off);
        s.z += __shfl_xor(s.z, off);
        s.w += __shfl_xor(s.w, off);
    }
    float4 inv;
    inv.x = 1.f / (s.x + 1e-16f);
    inv.y = 1.f / (s.y + 1e-16f);
    inv.z = 1.f / (s.z + 1e-16f);
    inv.w = 1.f / (s.w + 1e-16f);

    // consume: 4 edge slots x 16 channel-lanes (8 fp16 ch each = 16B load)
    int eslot = lane >> 4, cl16 = lane & 15, head = cl16 >> 2;
    const __half* hbase = H16 + cl16 * 8;
    const float* pA = (const float*)eA;
    float acc8[8];
    #pragma unroll
    for (int k = 0; k < 8; k++) acc8[k] = 0.f;

    #pragma unroll 4
    for (int i = eslot; i < nst; i += 4) {
        int src = srcA[i];
        float p = pA[i * 4 + head];
        float4 raw = *(const float4*)(hbase + (size_t)src * 128);
        const __half2* hp = (const __half2*)&raw;
        float2 f0 = __half22float2(hp[0]);
        float2 f1 = __half22float2(hp[1]);
        float2 f2 = __half22float2(hp[2]);
        float2 f3 = __half22float2(hp[3]);
        acc8[0] += p * f0.x; acc8[1] += p * f0.y;
        acc8[2] += p * f1.x; acc8[3] += p * f1.y;
        acc8[4] += p * f2.x; acc8[5] += p * f2.y;
        acc8[6] += p * f3.x; acc8[7] += p * f3.y;
    }
    // overflow chunks (deg > CH, rare): restage then consume
    for (int cb = beg + CH; cb < end; cb += CH) {
        int cnt = min(end - cb, CH);
        for (int idx = lane; idx < cnt; idx += 64) {
            int src = col[cb + idx];
            float4 av = *(const float4*)&a_s[src * 4];
            float4 e = leaky4(av, ad4);
            float4 p;
            p.x = __expf(e.x - m.x); p.y = __expf(e.y - m.y);
            p.z = __expf(e.z - m.z); p.w = __expf(e.w - m.w);
            srcA[idx] = src; eA[idx] = p;
        }
        #pragma unroll 4
        for (int i = eslot; i < cnt; i += 4) {
            int src = srcA[i];
            float p = pA[i * 4 + head];
            float4 raw = *(const float4*)(hbase + (size_t)src * 128);
            const __half2* hp = (const __half2*)&raw;
            float2 f0 = __half22float2(hp[0]);
            float2 f1 = __half22float2(hp[1]);
            float2 f2 = __half22float2(hp[2]);
            float2 f3 = __half22float2(hp[3]);
            acc8[0] += p * f0.x; acc8[1] += p * f0.y;
            acc8[2] += p * f1.x; acc8[3] += p * f1.y;
            acc8[4] += p * f2.x; acc8[5] += p * f2.y;
            acc8[6] += p * f3.x; acc8[7] += p * f3.y;
        }
    }

    #pragma unroll
    for (int k = 0; k < 8; k++) {
        acc8[k] += __shfl_xor(acc8[k], 16);
        acc8[k] += __shfl_xor(acc8[k], 32);
    }
    if (eslot == 0) {
        float ih = sel4(inv, head);
        const float* bp = &bias[cl16 * 8];
        float o[8];
        #pragma unroll
        for (int k = 0; k < 8; k++) {
            o[k] = acc8[k] * ih + bp[k];
            if (DO_ELU) o[k] = o[k] > 0.f ? o[k] : expm1f(o[k]);
        }
        float* op = &Hout[(size_t)node * 128 + cl16 * 8];
        *(float4*)&op[0] = make_float4(o[0], o[1], o[2], o[3]);
        *(float4*)&op[4] = make_float4(o[4], o[5], o[6], o[7]);
    }
}

// ---------------- Output projection [N,128]@[128,8] ----------------

__global__ __launch_bounds__(256) void k_out(
    const float* __restrict__ Hin, const float* __restrict__ Wout,
    const float* __restrict__ bout, float* __restrict__ out) {
    __shared__ float Wl[128 * 8];
    __shared__ float bl[8];
    int t = threadIdx.x;
    for (int j = t; j < 1024; j += 256) Wl[j] = Wout[j];
    if (t < 8) bl[t] = bout[t];
    __syncthreads();
    int gid = blockIdx.x * 256 + t;
    int row = gid >> 3, o = gid & 7;
    if (row >= N_NODES) return;
    const float* hr = &Hin[row * 128];
    float acc = bl[o];
    #pragma unroll
    for (int k4 = 0; k4 < 32; k4++) {
        float4 hv = *(const float4*)&hr[k4 * 4];
        acc += hv.x * Wl[(k4 * 4 + 0) * 8 + o];
        acc += hv.y * Wl[(k4 * 4 + 1) * 8 + o];
        acc += hv.z * Wl[(k4 * 4 + 2) * 8 + o];
        acc += hv.w * Wl[(k4 * 4 + 3) * 8 + o];
    }
    out[row * 8 + o] = acc;
}

// ---------------- launch ----------------

extern "C" void kernel_launch(void* const* d_in, const int* in_sizes, int n_in,
                              void* d_out, int out_size, void* d_ws, size_t ws_size,
                              hipStream_t stream) {
    const float* x     = (const float*)d_in[0];
    const int*   ei    = (const int*)d_in[1];
    const float* W1    = (const float*)d_in[2];
    const float* attS1 = (const float*)d_in[3];
    const float* attD1 = (const float*)d_in[4];
    const float* b1    = (const float*)d_in[5];
    const float* W2    = (const float*)d_in[6];
    const float* attS2 = (const float*)d_in[7];
    const float* attD2 = (const float*)d_in[8];
    const float* b2    = (const float*)d_in[9];
    const float* Wout  = (const float*)d_in[10];
    const float* bout  = (const float*)d_in[11];
    float* out = (float*)d_out;

    char* ws = (char*)d_ws;
    size_t off = 0;
    auto alloc = [&](size_t bytes) -> void* {
        void* p = ws + off;
        off += (bytes + 255) & ~(size_t)255;
        return p;
    };
    float*  hB        = (float*)alloc((size_t)N_NODES * 128 * 4);
    __half* h16       = (__half*)alloc((size_t)N_NODES * 128 * 2);
    float*  a_s       = (float*)alloc((size_t)N_NODES * 4 * 4);
    float*  a_d       = (float*)alloc((size_t)N_NODES * 4 * 4);
    int*    deg       = (int*)alloc((size_t)N_NODES * 4);
    int*    row_start = (int*)alloc((size_t)(N_NODES + 1) * 4);
    int*    part      = (int*)alloc(256 * 4);
    int*    col       = (int*)alloc((size_t)NE_TOT * 4);
    int*    histG     = (int*)alloc((size_t)NWA * NBKT * 4);
    int2*   pairs     = (int2*)hB;   // alias: hB not live during CSR build

    hipMemsetAsync(deg, 0, (size_t)N_NODES * 4, stream);
    int nbE = (NE_TOT + 255) / 256;
    int nbS = (N_NODES + 1023) / 1024;   // 49
    k_hist<<<nbE, 256, 0, stream>>>(ei, deg);
    k_scan1<<<nbS, 256, 0, stream>>>(deg, part);
    k_scan2<<<1, 256, 0, stream>>>(part, row_start, nbS);
    k_scan3<<<nbS, 256, 0, stream>>>(deg, part, row_start);

    k_binhist<<<NWA, 256, 0, stream>>>(ei, histG);
    k_binscan<<<(NBKT + 255) / 256, 256, 0, stream>>>(histG, row_start);
    k_binscatter<<<NWA, 256, 0, stream>>>(ei, histG, pairs);
    k_bucketsort<<<NBKT, 256, 0, stream>>>(pairs, row_start, col);

    int nbG = (N_NODES + 31) / 32;
    int nbA = (N_NODES + 3) / 4;
    k_gemm_att<<<nbG, 256, 0, stream>>>(x, W1, attS1, attD1, h16, a_s, a_d);
    k_agg<1><<<nbA, 256, 0, stream>>>(h16, a_s, a_d, row_start, col, b1, hB);
    k_gemm_att<<<nbG, 256, 0, stream>>>(hB, W2, attS2, attD2, h16, a_s, a_d);
    k_agg<0><<<nbA, 256, 0, stream>>>(h16, a_s, a_d, row_start, col, b2, hB);

    int nbO = (N_NODES * 8 + 255) / 256;
    k_out<<<nbO, 256, 0, stream>>>(hB, Wout, bout, out);
}

// Round 6
// 300.018 us; speedup vs baseline: 1.8093x; 1.2368x over previous
//
#include <hip/hip_runtime.h>
#include <hip/hip_fp16.h>
#include <math.h>

#define N_NODES 50000
#define E_EDGES 1600000
#define NE_TOT  (E_EDGES + N_NODES)

// bucketed scatter geometry
#define BSH 7                                   // 128 nodes per bucket
#define NBKT ((N_NODES + 127) >> 7)             // 391 buckets
#define EPW 8192                                // edges per A-pass workgroup
#define NWA ((NE_TOT + EPW - 1) / EPW)          // 202 workgroups

#define CH 128                                  // staged edges per node chunk

// ---------------- bucketed CSR build (no global hist/scan passes) ----------------

// A1: per-workgroup histogram over NBKT buckets (128 dst nodes each)
__global__ __launch_bounds__(256) void k_binhist(const int* __restrict__ ei,
                                                 int* __restrict__ histG) {
    __shared__ int h[NBKT];
    int t = threadIdx.x;
    for (int i = t; i < NBKT; i += 256) h[i] = 0;
    __syncthreads();
    int base = blockIdx.x * EPW;
    #pragma unroll 4
    for (int j = 0; j < EPW / 256; j++) {
        int e = base + t + 256 * j;
        if (e < NE_TOT) {
            int d = (e < E_EDGES) ? ei[E_EDGES + e] : (e - E_EDGES);
            atomicAdd(&h[d >> BSH], 1);
        }
    }
    __syncthreads();
    for (int i = t; i < NBKT; i += 256) histG[blockIdx.x * NBKT + i] = h[i];
}

// A2: per-bucket: column-scan hist over workgroups -> relative offsets + totals
__global__ void k_bktscan(int* __restrict__ histG, int* __restrict__ bktTotal) {
    int b = blockIdx.x * 256 + threadIdx.x;
    if (b >= NBKT) return;
    int run = 0;
    for (int w = 0; w < NWA; w++) {
        int v = histG[w * NBKT + b];
        histG[w * NBKT + b] = run;
        run += v;
    }
    bktTotal[b] = run;
}

// A3: single block: exclusive scan of bucket totals -> bucket bases
__global__ __launch_bounds__(512) void k_bktbase(const int* __restrict__ bktTotal,
                                                 int* __restrict__ bktBase,
                                                 int* __restrict__ row_start) {
    __shared__ int sc[512];
    int t = threadIdx.x;
    int v = (t < NBKT) ? bktTotal[t] : 0;
    sc[t] = v;
    __syncthreads();
    for (int d = 1; d < 512; d <<= 1) {
        int x = (t >= d) ? sc[t - d] : 0;
        __syncthreads();
        sc[t] += x;
        __syncthreads();
    }
    if (t < NBKT) bktBase[t] = sc[t] - v;
    if (t == NBKT - 1) { bktBase[NBKT] = sc[t]; row_start[N_NODES] = sc[t]; }
}

// A4: append (src,dst) pairs into this wg's private per-bucket streams
__global__ __launch_bounds__(256) void k_binscatter(const int* __restrict__ ei,
                                                    const int* __restrict__ histG,
                                                    const int* __restrict__ bktBase,
                                                    int2* __restrict__ pairs) {
    __shared__ int lofs[NBKT];
    int t = threadIdx.x;
    for (int i = t; i < NBKT; i += 256)
        lofs[i] = bktBase[i] + histG[blockIdx.x * NBKT + i];
    __syncthreads();
    int base = blockIdx.x * EPW;
    #pragma unroll 4
    for (int j = 0; j < EPW / 256; j++) {
        int e = base + t + 256 * j;
        if (e < NE_TOT) {
            int s, d;
            if (e < E_EDGES) { s = ei[e]; d = ei[E_EDGES + e]; }
            else             { s = d = e - E_EDGES; }
            int pos = atomicAdd(&lofs[d >> BSH], 1);
            pairs[pos] = make_int2(s, d);
        }
    }
}

// B: one workgroup per bucket; derive per-node row_start (LDS hist+scan) and
//    scatter src into the dense col window
__global__ __launch_bounds__(256) void k_bucketsort(const int2* __restrict__ pairs,
                                                    const int* __restrict__ bktBase,
                                                    int* __restrict__ row_start,
                                                    int* __restrict__ col) {
    __shared__ int cnt[1 << BSH];
    __shared__ int sc[1 << BSH];
    __shared__ int cur[1 << BSH];
    int b = blockIdx.x, t = threadIdx.x;
    int nbeg = b << BSH;
    int ebeg = bktBase[b], eend = bktBase[b + 1];
    if (t < (1 << BSH)) cnt[t] = 0;
    __syncthreads();
    for (int j = ebeg + t; j < eend; j += 256)
        atomicAdd(&cnt[pairs[j].y - nbeg], 1);
    __syncthreads();
    int v = (t < (1 << BSH)) ? cnt[t] : 0;
    if (t < (1 << BSH)) sc[t] = v;
    __syncthreads();
    for (int d = 1; d < (1 << BSH); d <<= 1) {
        int x = 0;
        if (t < (1 << BSH) && t >= d) x = sc[t - d];
        __syncthreads();
        if (t < (1 << BSH)) sc[t] += x;
        __syncthreads();
    }
    if (t < (1 << BSH)) {
        int pos = ebeg + sc[t] - v;      // exclusive
        cur[t] = pos;
        int node = nbeg + t;
        if (node < N_NODES) row_start[node] = pos;
    }
    __syncthreads();
    for (int j = ebeg + t; j < eend; j += 256) {
        int2 p = pairs[j];
        int pos = atomicAdd(&cur[p.y - nbeg], 1);
        col[pos] = p.x;
    }
}

// ---------------- GEMM (128x128) + attention logits ----------------
// writes h only as fp16 (gather copy); logits computed fp32 in epilogue

__global__ __launch_bounds__(256) void k_gemm_att(
    const float* __restrict__ X, const float* __restrict__ W,
    const float* __restrict__ attS, const float* __restrict__ attD,
    __half* __restrict__ H16, float* __restrict__ a_s, float* __restrict__ a_d) {
    __shared__ float Wl[64 * 128];
    __shared__ float xs[32 * 64];
    int t = threadIdx.x;
    int g = t >> 5, cl = t & 31, c4 = cl * 4;
    int rowbase = blockIdx.x * 32;
    float4 acc[4];
    #pragma unroll
    for (int rr = 0; rr < 4; rr++) acc[rr] = make_float4(0.f, 0.f, 0.f, 0.f);

    for (int kp = 0; kp < 2; kp++) {
        __syncthreads();
        #pragma unroll
        for (int j = 0; j < 8; j++) {
            int f4 = t + 256 * j;
            int kk = f4 >> 5, cg = f4 & 31;
            *(float4*)&Wl[kk * 128 + cg * 4] =
                *(const float4*)&W[(kp * 64 + kk) * 128 + cg * 4];
        }
        #pragma unroll
        for (int j = 0; j < 2; j++) {
            int f4 = t + 256 * j;
            int r = f4 >> 4, k4 = f4 & 15;
            int grow = rowbase + r;
            float4 xv = make_float4(0.f, 0.f, 0.f, 0.f);
            if (grow < N_NODES) xv = *(const float4*)&X[grow * 128 + kp * 64 + k4 * 4];
            *(float4*)&xs[r * 64 + k4 * 4] = xv;
        }
        __syncthreads();
        #pragma unroll
        for (int k4 = 0; k4 < 16; k4++) {
            float4 xv[4];
            #pragma unroll
            for (int rr = 0; rr < 4; rr++)
                xv[rr] = *(float4*)&xs[(g * 4 + rr) * 64 + k4 * 4];
            #pragma unroll
            for (int kk = 0; kk < 4; kk++) {
                float4 wv = *(float4*)&Wl[(k4 * 4 + kk) * 128 + c4];
                #pragma unroll
                for (int rr = 0; rr < 4; rr++) {
                    float xc = (kk == 0) ? xv[rr].x : (kk == 1) ? xv[rr].y
                             : (kk == 2) ? xv[rr].z : xv[rr].w;
                    acc[rr].x += xc * wv.x;
                    acc[rr].y += xc * wv.y;
                    acc[rr].z += xc * wv.z;
                    acc[rr].w += xc * wv.w;
                }
            }
        }
    }

    float4 as4 = *(const float4*)&attS[c4];
    float4 ad4 = *(const float4*)&attD[c4];
    int head = cl >> 3;
    #pragma unroll
    for (int rr = 0; rr < 4; rr++) {
        int grow = rowbase + g * 4 + rr;
        float4 a = acc[rr];
        if (grow < N_NODES) {
            __half2 lo = __floats2half2_rn(a.x, a.y);
            __half2 hi = __floats2half2_rn(a.z, a.w);
            uint2 pk;
            pk.x = *(unsigned int*)&lo;
            pk.y = *(unsigned int*)&hi;
            *(uint2*)&H16[(size_t)grow * 128 + c4] = pk;
        }
        float ps = a.x * as4.x + a.y * as4.y + a.z * as4.z + a.w * as4.w;
        float pd = a.x * ad4.x + a.y * ad4.y + a.z * ad4.z + a.w * ad4.w;
        ps += __shfl_xor(ps, 1); ps += __shfl_xor(ps, 2); ps += __shfl_xor(ps, 4);
        pd += __shfl_xor(pd, 1); pd += __shfl_xor(pd, 2); pd += __shfl_xor(pd, 4);
        if ((cl & 7) == 0 && grow < N_NODES) {
            a_s[grow * 4 + head] = ps;
            a_d[grow * 4 + head] = pd;
        }
    }
}

// ---------------- Attention aggregation (MODE 1: +ELU->Hout; MODE 0: fused out-proj) ----

__device__ inline float sel4(float4 v, int i) {
    float r = v.x;
    if (i == 1) r = v.y;
    if (i == 2) r = v.z;
    if (i == 3) r = v.w;
    return r;
}

__device__ inline float4 leaky4(float4 a, float4 b) {
    float4 e;
    e.x = a.x + b.x; e.x = e.x > 0.f ? e.x : 0.2f * e.x;
    e.y = a.y + b.y; e.y = e.y > 0.f ? e.y : 0.2f * e.y;
    e.z = a.z + b.z; e.z = e.z > 0.f ? e.z : 0.2f * e.z;
    e.w = a.w + b.w; e.w = e.w > 0.f ? e.w : 0.2f * e.w;
    return e;
}

template<int MODE>   // 1: layer-1 (ELU, write Hout fp32); 0: layer-2 (project to out)
__global__ __launch_bounds__(256) void k_agg(
    const __half* __restrict__ H16, const float* __restrict__ a_s,
    const float* __restrict__ a_d, const int* __restrict__ row_start,
    const int* __restrict__ col, const float* __restrict__ bias,
    float* __restrict__ Hout,
    const float* __restrict__ Wout, const float* __restrict__ bout,
    float* __restrict__ out) {
    __shared__ float4 eS[4][CH];    // staged e -> p per wave
    __shared__ int    sS[4][CH];    // staged src per wave
    __shared__ float  WoT[(MODE == 0) ? 1024 : 1];  // transposed Wout [8][128]
    __shared__ float  boL[(MODE == 0) ? 8 : 1];

    if (MODE == 0) {
        for (int j = threadIdx.x; j < 1024; j += 256) {
            int o = j >> 7, k = j & 127;
            WoT[o * 128 + k] = Wout[k * 8 + o];
        }
        if (threadIdx.x < 8) boL[threadIdx.x] = bout[threadIdx.x];
        __syncthreads();
    }

    int wid = threadIdx.x >> 6;
    int lane = threadIdx.x & 63;
    int node = blockIdx.x * 4 + wid;
    if (node >= N_NODES) return;
    int beg = row_start[node], end = row_start[node + 1];
    int deg = end - beg;
    float4 ad4 = *(const float4*)&a_d[node * 4];
    float4* eA = eS[wid];
    int*    srcA = sS[wid];

    // pass 1: stage {src, e4} for first CH edges, track running max only
    float4 m = make_float4(-1e30f, -1e30f, -1e30f, -1e30f);
    for (int j = beg + lane; j < end; j += 64) {
        int src = col[j];
        float4 av = *(const float4*)&a_s[src * 4];
        float4 e = leaky4(av, ad4);
        int idx = j - beg;
        if (idx < CH) { srcA[idx] = src; eA[idx] = e; }
        m.x = fmaxf(m.x, e.x); m.y = fmaxf(m.y, e.y);
        m.z = fmaxf(m.z, e.z); m.w = fmaxf(m.w, e.w);
    }
    #pragma unroll
    for (int off = 32; off > 0; off >>= 1) {
        m.x = fmaxf(m.x, __shfl_xor(m.x, off));
        m.y = fmaxf(m.y, __shfl_xor(m.y, off));
        m.z = fmaxf(m.z, __shfl_xor(m.z, off));
        m.w = fmaxf(m.w, __shfl_xor(m.w, off));
    }

    // convert staged e -> p = exp(e-m), accumulate partial denom
    float4 s = make_float4(0.f, 0.f, 0.f, 0.f);
    int nst = min(deg, CH);
    for (int idx = lane; idx < nst; idx += 64) {
        float4 e = eA[idx];
        float4 p;
        p.x = __expf(e.x - m.x); p.y = __expf(e.y - m.y);
        p.z = __expf(e.z - m.z); p.w = __expf(e.w - m.w);
        s.x += p.x; s.y += p.y; s.z += p.z; s.w += p.w;
        eA[idx] = p;
    }
    // tail edges beyond CH (rare): recompute for denom
    for (int j = beg + CH + lane; j < end; j += 64) {
        int src = col[j];
        float4 av = *(const float4*)&a_s[src * 4];
        float4 e = leaky4(av, ad4);
        s.x += __expf(e.x - m.x); s.y += __expf(e.y - m.y);
        s.z += __expf(e.z - m.z); s.w += __expf(e.w - m.w);
    }
    #pragma unroll
    for (int off = 32; off > 0; off >>= 1) {
        s.x += __shfl_xor(s.x, off);
        s.y += __shfl_xor(s.y, off);
        s.z += __shfl_xor(s.z, off);
        s.w += __shfl_xor(s.w, off);
    }
    float4 inv;
    inv.x = 1.f / (s.x + 1e-16f);
    inv.y = 1.f / (s.y + 1e-16f);
    inv.z = 1.f / (s.z + 1e-16f);
    inv.w = 1.f / (s.w + 1e-16f);

    // consume: 4 edge slots x 16 channel-lanes (8 fp16 ch each = 16B load)
    int eslot = lane >> 4, cl16 = lane & 15, head = cl16 >> 2;
    const __half* hbase = H16 + cl16 * 8;
    const float* pA = (const float*)eA;
    float acc8[8];
    #pragma unroll
    for (int k = 0; k < 8; k++) acc8[k] = 0.f;

    #pragma unroll 4
    for (int i = eslot; i < nst; i += 4) {
        int src = srcA[i];
        float p = pA[i * 4 + head];
        float4 raw = *(const float4*)(hbase + (size_t)src * 128);
        const __half2* hp = (const __half2*)&raw;
        float2 f0 = __half22float2(hp[0]);
        float2 f1 = __half22float2(hp[1]);
        float2 f2 = __half22float2(hp[2]);
        float2 f3 = __half22float2(hp[3]);
        acc8[0] = fmaf(p, f0.x, acc8[0]); acc8[1] = fmaf(p, f0.y, acc8[1]);
        acc8[2] = fmaf(p, f1.x, acc8[2]); acc8[3] = fmaf(p, f1.y, acc8[3]);
        acc8[4] = fmaf(p, f2.x, acc8[4]); acc8[5] = fmaf(p, f2.y, acc8[5]);
        acc8[6] = fmaf(p, f3.x, acc8[6]); acc8[7] = fmaf(p, f3.y, acc8[7]);
    }
    // overflow chunks (deg > CH, rare): restage then consume
    for (int cb = beg + CH; cb < end; cb += CH) {
        int cnt = min(end - cb, CH);
        for (int idx = lane; idx < cnt; idx += 64) {
            int src = col[cb + idx];
            float4 av = *(const float4*)&a_s[src * 4];
            float4 e = leaky4(av, ad4);
            float4 p;
            p.x = __expf(e.x - m.x); p.y = __expf(e.y - m.y);
            p.z = __expf(e.z - m.z); p.w = __expf(e.w - m.w);
            srcA[idx] = src; eA[idx] = p;
        }
        #pragma unroll 4
        for (int i = eslot; i < cnt; i += 4) {
            int src = srcA[i];
            float p = pA[i * 4 + head];
            float4 raw = *(const float4*)(hbase + (size_t)src * 128);
            const __half2* hp = (const __half2*)&raw;
            float2 f0 = __half22float2(hp[0]);
            float2 f1 = __half22float2(hp[1]);
            float2 f2 = __half22float2(hp[2]);
            float2 f3 = __half22float2(hp[3]);
            acc8[0] = fmaf(p, f0.x, acc8[0]); acc8[1] = fmaf(p, f0.y, acc8[1]);
            acc8[2] = fmaf(p, f1.x, acc8[2]); acc8[3] = fmaf(p, f1.y, acc8[3]);
            acc8[4] = fmaf(p, f2.x, acc8[4]); acc8[5] = fmaf(p, f2.y, acc8[5]);
            acc8[6] = fmaf(p, f3.x, acc8[6]); acc8[7] = fmaf(p, f3.y, acc8[7]);
        }
    }

    #pragma unroll
    for (int k = 0; k < 8; k++) {
        acc8[k] += __shfl_xor(acc8[k], 16);
        acc8[k] += __shfl_xor(acc8[k], 32);
    }

    float ih = sel4(inv, head);
    if (MODE == 1) {
        if (eslot == 0) {
            const float* bp = &bias[cl16 * 8];
            float o[8];
            #pragma unroll
            for (int k = 0; k < 8; k++) {
                o[k] = acc8[k] * ih + bp[k];
                o[k] = o[k] > 0.f ? o[k] : expm1f(o[k]);
            }
            float* op = &Hout[(size_t)node * 128 + cl16 * 8];
            *(float4*)&op[0] = make_float4(o[0], o[1], o[2], o[3]);
            *(float4*)&op[4] = make_float4(o[4], o[5], o[6], o[7]);
        }
    } else {
        // fused output projection: h2 = acc*ih + b2 (all lanes hold it),
        // each eslot computes 2 of the 8 outputs
        const float* bp = &bias[cl16 * 8];
        float4 oa, ob;
        oa.x = acc8[0] * ih + bp[0]; oa.y = acc8[1] * ih + bp[1];
        oa.z = acc8[2] * ih + bp[2]; oa.w = acc8[3] * ih + bp[3];
        ob.x = acc8[4] * ih + bp[4]; ob.y = acc8[5] * ih + bp[5];
        ob.z = acc8[6] * ih + bp[6]; ob.w = acc8[7] * ih + bp[7];
        int o0 = eslot * 2;
        float p0 = 0.f, p1 = 0.f;
        {
            float4 wa = *(float4*)&WoT[o0 * 128 + cl16 * 8];
            float4 wb = *(float4*)&WoT[o0 * 128 + cl16 * 8 + 4];
            p0 = oa.x * wa.x + oa.y * wa.y + oa.z * wa.z + oa.w * wa.w
               + ob.x * wb.x + ob.y * wb.y + ob.z * wb.z + ob.w * wb.w;
            float4 wc = *(float4*)&WoT[(o0 + 1) * 128 + cl16 * 8];
            float4 wd = *(float4*)&WoT[(o0 + 1) * 128 + cl16 * 8 + 4];
            p1 = oa.x * wc.x + oa.y * wc.y + oa.z * wc.z + oa.w * wc.w
               + ob.x * wd.x + ob.y * wd.y + ob.z * wd.z + ob.w * wd.w;
        }
        #pragma unroll
        for (int d = 1; d <= 8; d <<= 1) {
            p0 += __shfl_xor(p0, d);
            p1 += __shfl_xor(p1, d);
        }
        if (cl16 == 0) {
            float2 ov = make_float2(p0 + boL[o0], p1 + boL[o0 + 1]);
            *(float2*)&out[(size_t)node * 8 + o0] = ov;
        }
    }
}

// ---------------- launch ----------------

extern "C" void kernel_launch(void* const* d_in, const int* in_sizes, int n_in,
                              void* d_out, int out_size, void* d_ws, size_t ws_size,
                              hipStream_t stream) {
    const float* x     = (const float*)d_in[0];
    const int*   ei    = (const int*)d_in[1];
    const float* W1    = (const float*)d_in[2];
    const float* attS1 = (const float*)d_in[3];
    const float* attD1 = (const float*)d_in[4];
    const float* b1    = (const float*)d_in[5];
    const float* W2    = (const float*)d_in[6];
    const float* attS2 = (const float*)d_in[7];
    const float* attD2 = (const float*)d_in[8];
    const float* b2    = (const float*)d_in[9];
    const float* Wout  = (const float*)d_in[10];
    const float* bout  = (const float*)d_in[11];
    float* out = (float*)d_out;

    char* ws = (char*)d_ws;
    size_t off = 0;
    auto alloc = [&](size_t bytes) -> void* {
        void* p = ws + off;
        off += (bytes + 255) & ~(size_t)255;
        return p;
    };
    float*  hB        = (float*)alloc((size_t)N_NODES * 128 * 4);
    __half* h16       = (__half*)alloc((size_t)N_NODES * 128 * 2);
    float*  a_s       = (float*)alloc((size_t)N_NODES * 4 * 4);
    float*  a_d       = (float*)alloc((size_t)N_NODES * 4 * 4);
    int*    row_start = (int*)alloc((size_t)(N_NODES + 1) * 4);
    int*    col       = (int*)alloc((size_t)NE_TOT * 4);
    int*    histG     = (int*)alloc((size_t)NWA * NBKT * 4);
    int*    bktTotal  = (int*)alloc((size_t)NBKT * 4);
    int*    bktBase   = (int*)alloc((size_t)(NBKT + 1) * 4);
    int2*   pairs     = (int2*)hB;   // alias: hB not live during CSR build

    k_binhist<<<NWA, 256, 0, stream>>>(ei, histG);
    k_bktscan<<<(NBKT + 255) / 256, 256, 0, stream>>>(histG, bktTotal);
    k_bktbase<<<1, 512, 0, stream>>>(bktTotal, bktBase, row_start);
    k_binscatter<<<NWA, 256, 0, stream>>>(ei, histG, bktBase, pairs);
    k_bucketsort<<<NBKT, 256, 0, stream>>>(pairs, bktBase, row_start, col);

    int nbG = (N_NODES + 31) / 32;
    int nbA = (N_NODES + 3) / 4;
    k_gemm_att<<<nbG, 256, 0, stream>>>(x, W1, attS1, attD1, h16, a_s, a_d);
    k_agg<1><<<nbA, 256, 0, stream>>>(h16, a_s, a_d, row_start, col, b1, hB,
                                      Wout, bout, out);
    k_gemm_att<<<nbG, 256, 0, stream>>>(hB, W2, attS2, attD2, h16, a_s, a_d);
    k_agg<0><<<nbA, 256, 0, stream>>>(h16, a_s, a_d, row_start, col, b2, hB,
                                      Wout, bout, out);
}